// Round 7
// baseline (466.028 us; speedup 1.0000x reference)
//
#include <hip/hip_runtime.h>
#include <math.h>

#define EPS 1e-6f

constexpr int B_ = 32;
constexpr int T_ = 8192;
constexpr int F_ = 128;
constexpr int FG = F_ / 4;          // 32 float4 per timestep row
constexpr int SLOTS = 8;            // chunks handled per block
constexpr int NC = 256;             // chunks per batch row
constexpr int L  = T_ / NC;         // 32 timesteps per chunk
constexpr int GROUPS = NC / SLOTS;  // 32 blocks per batch row
constexpr int NBLK = B_ * GROUPS;   // 1024 blocks

// fast pow for strictly-positive base
__device__ __forceinline__ float fpow(float b, float e) {
    return exp2f(e * __log2f(b));
}

__global__ __launch_bounds__(256, 4) void pcen_onepass(
    const float4* __restrict__ x4,
    const float4* __restrict__ state4,
    const float*  __restrict__ log_s,
    const float*  __restrict__ log_alpha,
    const float*  __restrict__ log_delta,
    const float*  __restrict__ log_r,
    float4* __restrict__ y4,
    float4* __restrict__ new_state4,
    float4* __restrict__ G4,        // [B][GROUPS][FG] group aggregates
    int*    __restrict__ flags,     // [B][GROUPS]
    int*    __restrict__ ticket)
{
    __shared__ float4 lds_S[SLOTS][FG];
    __shared__ int vid_s;

    // ticket-ordered virtual block id: predecessors always have smaller vid
    // => they are already resident or retired => spin-wait cannot deadlock,
    // independent of HW dispatch order.
    if (threadIdx.x == 0) {
        vid_s = __hip_atomic_fetch_add(ticket, 1, __ATOMIC_RELAXED,
                                       __HIP_MEMORY_SCOPE_AGENT);
    }
    __syncthreads();
    const int vid = vid_s;
    const int b = vid % B_;     // (b, g) predecessors (g' < g) have vid' = g'*B+b < vid
    const int g = vid / B_;

    const int fg    = threadIdx.x & 31;
    const int slot  = threadIdx.x >> 5;
    const int chunk = g * SLOTS + slot;

    const float4 lsv = reinterpret_cast<const float4*>(log_s)[fg];
    const float s0 = expf(lsv.x), s1 = expf(lsv.y), s2 = expf(lsv.z), s3 = expf(lsv.w);
    const float a0 = 1.f - s0,   a1 = 1.f - s1,    a2 = 1.f - s2,    a3 = 1.f - s3;
    const float aL0 = fpow(a0, (float)L), aL1 = fpow(a1, (float)L),
                aL2 = fpow(a2, (float)L), aL3 = fpow(a3, (float)L);

    // ---- phase A: local chunk sum with zero carry (the single x read) ----
    const size_t xbase = ((size_t)b * T_ + (size_t)chunk * L) * FG + fg;
    const float4* xp = x4 + xbase;

    {
        float c0 = 0.f, c1 = 0.f, c2 = 0.f, c3 = 0.f;
        #pragma unroll
        for (int i = 0; i < L; ++i) {
            const float4 xv = xp[(size_t)i * FG];
            c0 = fmaf(a0, c0, s0 * xv.x);
            c1 = fmaf(a1, c1, s1 * xv.y);
            c2 = fmaf(a2, c2, s2 * xv.z);
            c3 = fmaf(a3, c3, s3 * xv.w);
        }
        lds_S[slot][fg] = make_float4(c0, c1, c2, c3);
    }
    __syncthreads();

    // ---- publish group aggregate G = sum_{k<8} aL^(7-k) * S_k ----
    if (slot == 0) {
        float gx = 0.f, gy = 0.f, gz = 0.f, gw = 0.f;
        #pragma unroll
        for (int k = 0; k < SLOTS; ++k) {
            const float4 Sv = lds_S[k][fg];
            gx = fmaf(aL0, gx, Sv.x);
            gy = fmaf(aL1, gy, Sv.y);
            gz = fmaf(aL2, gz, Sv.z);
            gw = fmaf(aL3, gw, Sv.w);
        }
        G4[((size_t)b * GROUPS + g) * FG + fg] = make_float4(gx, gy, gz, gw);
    }
    __threadfence();   // make G visible at agent scope before flag release
    __syncthreads();
    if (threadIdx.x == 0) {
        __hip_atomic_store(&flags[b * GROUPS + g], 1, __ATOMIC_RELEASE,
                           __HIP_MEMORY_SCOPE_AGENT);
    }

    // ---- phase B: wait on own-row predecessors (publish-before-wait!) ----
    if (g > 0) {
        if (threadIdx.x == 0) {
            for (int g2 = 0; g2 < g; ++g2) {
                while (__hip_atomic_load(&flags[b * GROUPS + g2],
                                         __ATOMIC_ACQUIRE,
                                         __HIP_MEMORY_SCOPE_AGENT) == 0) {
                    __builtin_amdgcn_s_sleep(2);
                }
            }
        }
        __syncthreads();
        __threadfence();   // no stale G lines in this XCD's caches
    }

    // aG = aL^8 via 3 squarings
    float t0 = aL0 * aL0, t1 = aL1 * aL1, t2 = aL2 * aL2, t3 = aL3 * aL3;
    t0 *= t0; t1 *= t1; t2 *= t2; t3 *= t3;
    const float aG0 = t0 * t0, aG1 = t1 * t1, aG2 = t2 * t2, aG3 = t3 * t3;

    // inter-group carry from aggregates (<=31 FMAs, L2-hot reads)
    float4 c = state4[(size_t)b * FG + fg];
    for (int g2 = 0; g2 < g; ++g2) {
        const float4 Gv = G4[((size_t)b * GROUPS + g2) * FG + fg];
        c.x = fmaf(aG0, c.x, Gv.x);
        c.y = fmaf(aG1, c.y, Gv.y);
        c.z = fmaf(aG2, c.z, Gv.z);
        c.w = fmaf(aG3, c.w, Gv.w);
    }
    // intra-group tail from LDS
    #pragma unroll
    for (int k = 0; k < SLOTS - 1; ++k) {
        if (k < slot) {
            const float4 Sv = lds_S[k][fg];
            c.x = fmaf(aL0, c.x, Sv.x);
            c.y = fmaf(aL1, c.y, Sv.y);
            c.z = fmaf(aL2, c.z, Sv.z);
            c.w = fmaf(aL3, c.w, Sv.w);
        }
    }

    // ---- phase C: stepwise recurrence + y (x re-read is cache-hot) ----
    const float4 lav = reinterpret_cast<const float4*>(log_alpha)[fg];
    const float4 ldv = reinterpret_cast<const float4*>(log_delta)[fg];
    const float4 lrv = reinterpret_cast<const float4*>(log_r)[fg];
    const float na0 = -expf(lav.x), na1 = -expf(lav.y), na2 = -expf(lav.z), na3 = -expf(lav.w);
    const float d0 = expf(ldv.x), d1 = expf(ldv.y), d2 = expf(ldv.z), d3 = expf(ldv.w);
    const float r0 = expf(lrv.x), r1 = expf(lrv.y), r2 = expf(lrv.z), r3 = expf(lrv.w);
    const float dr0 = fpow(d0, r0), dr1 = fpow(d1, r1);
    const float dr2 = fpow(d2, r2), dr3 = fpow(d3, r3);

    float4* yp = y4 + xbase;

    #pragma unroll
    for (int i = 0; i < L; ++i) {
        const float4 xv = xp[(size_t)i * FG];

        c.x = fmaf(a0, c.x, s0 * xv.x);
        c.y = fmaf(a1, c.y, s1 * xv.y);
        c.z = fmaf(a2, c.z, s2 * xv.z);
        c.w = fmaf(a3, c.w, s3 * xv.w);

        const float u0 = xv.x * exp2f(na0 * __log2f(EPS + c.x));
        const float u1 = xv.y * exp2f(na1 * __log2f(EPS + c.y));
        const float u2 = xv.z * exp2f(na2 * __log2f(EPS + c.z));
        const float u3 = xv.w * exp2f(na3 * __log2f(EPS + c.w));

        float4 yv;
        yv.x = exp2f(r0 * __log2f(u0 + d0)) - dr0;
        yv.y = exp2f(r1 * __log2f(u1 + d1)) - dr1;
        yv.z = exp2f(r2 * __log2f(u2 + d2)) - dr2;
        yv.w = exp2f(r3 * __log2f(u3 + d3)) - dr3;

        yp[(size_t)i * FG] = yv;
    }

    // final state = stepwise carry of the last chunk
    if (chunk == NC - 1) {
        new_state4[(size_t)b * FG + fg] = c;
    }
}

extern "C" void kernel_launch(void* const* d_in, const int* in_sizes, int n_in,
                              void* d_out, int out_size, void* d_ws, size_t ws_size,
                              hipStream_t stream)
{
    const float* x         = (const float*)d_in[0];
    const float* state     = (const float*)d_in[1];
    const float* log_s     = (const float*)d_in[2];
    const float* log_alpha = (const float*)d_in[3];
    const float* log_delta = (const float*)d_in[4];
    const float* log_r     = (const float*)d_in[5];

    float* y         = (float*)d_out;
    float* new_state = y + (size_t)B_ * T_ * F_;

    // ws layout: [0, 8192): ticket (1 int) + flags (NBLK ints), zeroed each call
    //            [8192, ...): G4 aggregates (B*GROUPS*FG float4 = 512 KB)
    int* ticket = (int*)d_ws;
    int* flags  = ticket + 1;
    float4* G4  = (float4*)((char*)d_ws + 8192);

    hipMemsetAsync(d_ws, 0, 8192, stream);

    pcen_onepass<<<dim3(NBLK), dim3(256), 0, stream>>>(
        (const float4*)x, (const float4*)state,
        log_s, log_alpha, log_delta, log_r,
        (float4*)y, (float4*)new_state,
        G4, flags, ticket);
}

// Round 8
// 195.052 us; speedup vs baseline: 2.3892x; 2.3892x over previous
//
#include <hip/hip_runtime.h>
#include <math.h>

#define EPS 1e-6f

constexpr int B_ = 32;
constexpr int T_ = 8192;
constexpr int F_ = 128;
constexpr int FG = F_ / 4;          // 32 float4 per timestep row
constexpr int SLOTS = 8;            // chunks handled per block
constexpr int NC = 256;             // chunks per batch row
constexpr int L  = T_ / NC;         // 32 timesteps per chunk
constexpr int GROUPS = NC / SLOTS;  // 32 blocks per batch row
constexpr int NBLK = B_ * GROUPS;   // 1024 blocks

// fast pow for strictly-positive base
__device__ __forceinline__ float fpow(float b, float e) {
    return exp2f(e * __log2f(b));
}

__global__ __launch_bounds__(256, 4) void pcen_coop(
    const float4* __restrict__ x4,
    const float4* __restrict__ state4,
    const float*  __restrict__ log_s,
    const float*  __restrict__ log_alpha,
    const float*  __restrict__ log_delta,
    const float*  __restrict__ log_r,
    float4* __restrict__ y4,
    float4* __restrict__ new_state4,
    float4* __restrict__ G4,        // [B][GROUPS][FG] group aggregates
    int*    __restrict__ bar)       // single arrive counter, zeroed per launch
{
    __shared__ float4 lds_S[SLOTS][FG];

    const int b = blockIdx.x % B_;
    const int g = blockIdx.x / B_;

    const int fg    = threadIdx.x & 31;
    const int slot  = threadIdx.x >> 5;
    const int chunk = g * SLOTS + slot;

    const float4 lsv = reinterpret_cast<const float4*>(log_s)[fg];
    const float s0 = expf(lsv.x), s1 = expf(lsv.y), s2 = expf(lsv.z), s3 = expf(lsv.w);
    const float a0 = 1.f - s0,   a1 = 1.f - s1,    a2 = 1.f - s2,    a3 = 1.f - s3;
    const float aL0 = fpow(a0, (float)L), aL1 = fpow(a1, (float)L),
                aL2 = fpow(a2, (float)L), aL3 = fpow(a3, (float)L);

    // ---- phase A: local chunk sum with zero carry (the single HBM x read) ----
    const size_t xbase = ((size_t)b * T_ + (size_t)chunk * L) * FG + fg;
    const float4* xp = x4 + xbase;

    {
        float c0 = 0.f, c1 = 0.f, c2 = 0.f, c3 = 0.f;
        #pragma unroll
        for (int i = 0; i < L; ++i) {
            const float4 xv = xp[(size_t)i * FG];
            c0 = fmaf(a0, c0, s0 * xv.x);
            c1 = fmaf(a1, c1, s1 * xv.y);
            c2 = fmaf(a2, c2, s2 * xv.z);
            c3 = fmaf(a3, c3, s3 * xv.w);
        }
        lds_S[slot][fg] = make_float4(c0, c1, c2, c3);
    }
    __syncthreads();

    // group aggregate G = combine of the 8 local sums (wave 0 only)
    if (slot == 0) {
        float gx = 0.f, gy = 0.f, gz = 0.f, gw = 0.f;
        #pragma unroll
        for (int k = 0; k < SLOTS; ++k) {
            const float4 Sv = lds_S[k][fg];
            gx = fmaf(aL0, gx, Sv.x);
            gy = fmaf(aL1, gy, Sv.y);
            gz = fmaf(aL2, gz, Sv.z);
            gw = fmaf(aL3, gw, Sv.w);
        }
        G4[((size_t)b * GROUPS + g) * FG + fg] = make_float4(gx, gy, gz, gw);
    }

    // ---- global arrive-and-wait barrier ----
    // G stores are wave 0; thread 0 (same wave) RELEASE-adds => one wbl2/block,
    // issued while L2 is still nearly clean. Polls are RELAXED (sc1 load, no
    // cache invalidate). ONE acquire fence after the barrier opens.
    if (threadIdx.x == 0) {
        __hip_atomic_fetch_add(bar, 1, __ATOMIC_RELEASE, __HIP_MEMORY_SCOPE_AGENT);
        while (__hip_atomic_load(bar, __ATOMIC_RELAXED, __HIP_MEMORY_SCOPE_AGENT) < NBLK) {
            __builtin_amdgcn_s_sleep(4);
        }
        __builtin_amdgcn_fence(__ATOMIC_ACQUIRE, "agent");
    }
    __syncthreads();

    // ---- phase B: carry from state + inter-group G prefix + intra-group LDS ----
    // aG = aL^SLOTS via 3 squarings
    float t0 = aL0 * aL0, t1 = aL1 * aL1, t2 = aL2 * aL2, t3 = aL3 * aL3;
    t0 *= t0; t1 *= t1; t2 *= t2; t3 *= t3;
    const float aG0 = t0 * t0, aG1 = t1 * t1, aG2 = t2 * t2, aG3 = t3 * t3;

    float4 c = state4[(size_t)b * FG + fg];
    for (int g2 = 0; g2 < g; ++g2) {
        const float4 Gv = G4[((size_t)b * GROUPS + g2) * FG + fg];
        c.x = fmaf(aG0, c.x, Gv.x);
        c.y = fmaf(aG1, c.y, Gv.y);
        c.z = fmaf(aG2, c.z, Gv.z);
        c.w = fmaf(aG3, c.w, Gv.w);
    }
    #pragma unroll
    for (int k = 0; k < SLOTS - 1; ++k) {
        if (k < slot) {
            const float4 Sv = lds_S[k][fg];
            c.x = fmaf(aL0, c.x, Sv.x);
            c.y = fmaf(aL1, c.y, Sv.y);
            c.z = fmaf(aL2, c.z, Sv.z);
            c.w = fmaf(aL3, c.w, Sv.w);
        }
    }

    // ---- phase C: stepwise recurrence + y (x re-read is L3-hot) ----
    const float4 lav = reinterpret_cast<const float4*>(log_alpha)[fg];
    const float4 ldv = reinterpret_cast<const float4*>(log_delta)[fg];
    const float4 lrv = reinterpret_cast<const float4*>(log_r)[fg];
    const float na0 = -expf(lav.x), na1 = -expf(lav.y), na2 = -expf(lav.z), na3 = -expf(lav.w);
    const float d0 = expf(ldv.x), d1 = expf(ldv.y), d2 = expf(ldv.z), d3 = expf(ldv.w);
    const float r0 = expf(lrv.x), r1 = expf(lrv.y), r2 = expf(lrv.z), r3 = expf(lrv.w);
    const float dr0 = fpow(d0, r0), dr1 = fpow(d1, r1);
    const float dr2 = fpow(d2, r2), dr3 = fpow(d3, r3);

    float4* yp = y4 + xbase;

    #pragma unroll
    for (int i = 0; i < L; ++i) {
        const float4 xv = xp[(size_t)i * FG];

        c.x = fmaf(a0, c.x, s0 * xv.x);
        c.y = fmaf(a1, c.y, s1 * xv.y);
        c.z = fmaf(a2, c.z, s2 * xv.z);
        c.w = fmaf(a3, c.w, s3 * xv.w);

        const float u0 = xv.x * exp2f(na0 * __log2f(EPS + c.x));
        const float u1 = xv.y * exp2f(na1 * __log2f(EPS + c.y));
        const float u2 = xv.z * exp2f(na2 * __log2f(EPS + c.z));
        const float u3 = xv.w * exp2f(na3 * __log2f(EPS + c.w));

        float4 yv;
        yv.x = exp2f(r0 * __log2f(u0 + d0)) - dr0;
        yv.y = exp2f(r1 * __log2f(u1 + d1)) - dr1;
        yv.z = exp2f(r2 * __log2f(u2 + d2)) - dr2;
        yv.w = exp2f(r3 * __log2f(u3 + d3)) - dr3;

        yp[(size_t)i * FG] = yv;
    }

    // final state = stepwise carry of the last chunk
    if (chunk == NC - 1) {
        new_state4[(size_t)b * FG + fg] = c;
    }
}

extern "C" void kernel_launch(void* const* d_in, const int* in_sizes, int n_in,
                              void* d_out, int out_size, void* d_ws, size_t ws_size,
                              hipStream_t stream)
{
    const float* x         = (const float*)d_in[0];
    const float* state     = (const float*)d_in[1];
    const float* log_s     = (const float*)d_in[2];
    const float* log_alpha = (const float*)d_in[3];
    const float* log_delta = (const float*)d_in[4];
    const float* log_r     = (const float*)d_in[5];

    float* y         = (float*)d_out;
    float* new_state = y + (size_t)B_ * T_ * F_;

    // ws layout: [0,256): barrier counter (zeroed each call)
    //            [256, ...): G4 aggregates (B*GROUPS*FG float4 = 512 KB)
    int* bar   = (int*)d_ws;
    float4* G4 = (float4*)((char*)d_ws + 256);

    hipMemsetAsync(d_ws, 0, 256, stream);

    pcen_coop<<<dim3(NBLK), dim3(256), 0, stream>>>(
        (const float4*)x, (const float4*)state,
        log_s, log_alpha, log_delta, log_r,
        (float4*)y, (float4*)new_state, G4, bar);
}

// Round 9
// 114.294 us; speedup vs baseline: 4.0775x; 1.7066x over previous
//
#include <hip/hip_runtime.h>
#include <math.h>

#define EPS 1e-6f

constexpr int B_ = 32;
constexpr int T_ = 8192;
constexpr int F_ = 128;
constexpr int FG = F_ / 4;          // 32 float4 per timestep row
constexpr int SLOTS = 8;            // chunks handled per block
constexpr int NC = 256;             // chunks per batch row
constexpr int L  = T_ / NC;         // 32 timesteps per chunk
constexpr int GROUPS = NC / SLOTS;  // 32 blocks per batch row
constexpr int NBLK = B_ * GROUPS;   // 1024 blocks (= 4/CU, co-resident)

// fast pow for strictly-positive base
__device__ __forceinline__ float fpow(float b, float e) {
    return exp2f(e * __log2f(b));
}

__global__ __launch_bounds__(256, 4) void pcen_lookback(
    const float4* __restrict__ x4,
    const float4* __restrict__ state4,
    const float*  __restrict__ log_s,
    const float*  __restrict__ log_alpha,
    const float*  __restrict__ log_delta,
    const float*  __restrict__ log_r,
    float4* __restrict__ y4,
    float4* __restrict__ new_state4,
    float4* __restrict__ G4,        // [B][GROUPS][FG] group aggregates
    int*    __restrict__ flags)     // [B][GROUPS], zeroed per launch
{
    __shared__ float4 lds_S[SLOTS][FG];

    // row-major-in-b mapping: all 32 groups of row b land on XCD (b % 8)
    const int b = blockIdx.x % B_;
    const int g = blockIdx.x / B_;

    const int fg    = threadIdx.x & 31;
    const int slot  = threadIdx.x >> 5;
    const int chunk = g * SLOTS + slot;

    const float4 lsv = reinterpret_cast<const float4*>(log_s)[fg];
    const float s0 = expf(lsv.x), s1 = expf(lsv.y), s2 = expf(lsv.z), s3 = expf(lsv.w);
    const float a0 = 1.f - s0,   a1 = 1.f - s1,    a2 = 1.f - s2,    a3 = 1.f - s3;
    const float aL0 = fpow(a0, (float)L), aL1 = fpow(a1, (float)L),
                aL2 = fpow(a2, (float)L), aL3 = fpow(a3, (float)L);

    // ---- phase A: local chunk sums with zero carry (the single HBM x read) ----
    const size_t xbase = ((size_t)b * T_ + (size_t)chunk * L) * FG + fg;
    const float4* xp = x4 + xbase;

    {
        float c0 = 0.f, c1 = 0.f, c2 = 0.f, c3 = 0.f;
        #pragma unroll
        for (int i = 0; i < L; ++i) {
            const float4 xv = xp[(size_t)i * FG];
            c0 = fmaf(a0, c0, s0 * xv.x);
            c1 = fmaf(a1, c1, s1 * xv.y);
            c2 = fmaf(a2, c2, s2 * xv.z);
            c3 = fmaf(a3, c3, s3 * xv.w);
        }
        lds_S[slot][fg] = make_float4(c0, c1, c2, c3);
    }
    __syncthreads();

    // group aggregate G = combine of the 8 local sums (wave 0 only)
    if (slot == 0) {
        float gx = 0.f, gy = 0.f, gz = 0.f, gw = 0.f;
        #pragma unroll
        for (int k = 0; k < SLOTS; ++k) {
            const float4 Sv = lds_S[k][fg];
            gx = fmaf(aL0, gx, Sv.x);
            gy = fmaf(aL1, gy, Sv.y);
            gz = fmaf(aL2, gz, Sv.z);
            gw = fmaf(aL3, gw, Sv.w);
        }
        G4[((size_t)b * GROUPS + g) * FG + fg] = make_float4(gx, gy, gz, gw);
    }
    __syncthreads();   // all G stores issued before the release flag

    // ---- publish own flag (distinct address per block; no RMW anywhere) ----
    if (threadIdx.x == 0) {
        __hip_atomic_store(&flags[b * GROUPS + g], 1, __ATOMIC_RELEASE,
                           __HIP_MEMORY_SCOPE_AGENT);
    }

    // ---- wait on own-row predecessors: RELAXED polls, ONE acquire fence ----
    if (g > 0) {
        if (threadIdx.x == 0) {
            for (int g2 = 0; g2 < g; ++g2) {
                while (__hip_atomic_load(&flags[b * GROUPS + g2],
                                         __ATOMIC_RELAXED,
                                         __HIP_MEMORY_SCOPE_AGENT) == 0) {
                    __builtin_amdgcn_s_sleep(1);
                }
            }
            __builtin_amdgcn_fence(__ATOMIC_ACQUIRE, "agent");
        }
        __syncthreads();
    }

    // ---- phase B: carry = state combined with predecessor aggregates ----
    // aG = aL^SLOTS via 3 squarings
    float t0 = aL0 * aL0, t1 = aL1 * aL1, t2 = aL2 * aL2, t3 = aL3 * aL3;
    t0 *= t0; t1 *= t1; t2 *= t2; t3 *= t3;
    const float aG0 = t0 * t0, aG1 = t1 * t1, aG2 = t2 * t2, aG3 = t3 * t3;

    float4 c = state4[(size_t)b * FG + fg];
    for (int g2 = 0; g2 < g; ++g2) {
        const float4 Gv = G4[((size_t)b * GROUPS + g2) * FG + fg];
        c.x = fmaf(aG0, c.x, Gv.x);
        c.y = fmaf(aG1, c.y, Gv.y);
        c.z = fmaf(aG2, c.z, Gv.z);
        c.w = fmaf(aG3, c.w, Gv.w);
    }
    #pragma unroll
    for (int k = 0; k < SLOTS - 1; ++k) {
        if (k < slot) {
            const float4 Sv = lds_S[k][fg];
            c.x = fmaf(aL0, c.x, Sv.x);
            c.y = fmaf(aL1, c.y, Sv.y);
            c.z = fmaf(aL2, c.z, Sv.z);
            c.w = fmaf(aL3, c.w, Sv.w);
        }
    }

    // ---- phase C: stepwise recurrence + y (x re-read is L3-hot) ----
    const float4 lav = reinterpret_cast<const float4*>(log_alpha)[fg];
    const float4 ldv = reinterpret_cast<const float4*>(log_delta)[fg];
    const float4 lrv = reinterpret_cast<const float4*>(log_r)[fg];
    const float na0 = -expf(lav.x), na1 = -expf(lav.y), na2 = -expf(lav.z), na3 = -expf(lav.w);
    const float d0 = expf(ldv.x), d1 = expf(ldv.y), d2 = expf(ldv.z), d3 = expf(ldv.w);
    const float r0 = expf(lrv.x), r1 = expf(lrv.y), r2 = expf(lrv.z), r3 = expf(lrv.w);
    const float dr0 = fpow(d0, r0), dr1 = fpow(d1, r1);
    const float dr2 = fpow(d2, r2), dr3 = fpow(d3, r3);

    float4* yp = y4 + xbase;

    #pragma unroll
    for (int i = 0; i < L; ++i) {
        const float4 xv = xp[(size_t)i * FG];

        c.x = fmaf(a0, c.x, s0 * xv.x);
        c.y = fmaf(a1, c.y, s1 * xv.y);
        c.z = fmaf(a2, c.z, s2 * xv.z);
        c.w = fmaf(a3, c.w, s3 * xv.w);

        const float u0 = xv.x * exp2f(na0 * __log2f(EPS + c.x));
        const float u1 = xv.y * exp2f(na1 * __log2f(EPS + c.y));
        const float u2 = xv.z * exp2f(na2 * __log2f(EPS + c.z));
        const float u3 = xv.w * exp2f(na3 * __log2f(EPS + c.w));

        float4 yv;
        yv.x = exp2f(r0 * __log2f(u0 + d0)) - dr0;
        yv.y = exp2f(r1 * __log2f(u1 + d1)) - dr1;
        yv.z = exp2f(r2 * __log2f(u2 + d2)) - dr2;
        yv.w = exp2f(r3 * __log2f(u3 + d3)) - dr3;

        yp[(size_t)i * FG] = yv;
    }

    // final state = stepwise carry of the last chunk
    if (chunk == NC - 1) {
        new_state4[(size_t)b * FG + fg] = c;
    }
}

extern "C" void kernel_launch(void* const* d_in, const int* in_sizes, int n_in,
                              void* d_out, int out_size, void* d_ws, size_t ws_size,
                              hipStream_t stream)
{
    const float* x         = (const float*)d_in[0];
    const float* state     = (const float*)d_in[1];
    const float* log_s     = (const float*)d_in[2];
    const float* log_alpha = (const float*)d_in[3];
    const float* log_delta = (const float*)d_in[4];
    const float* log_r     = (const float*)d_in[5];

    float* y         = (float*)d_out;
    float* new_state = y + (size_t)B_ * T_ * F_;

    // ws layout: [0, 8192): flags (NBLK ints, zeroed each call)
    //            [8192, ...): G4 aggregates (B*GROUPS*FG float4 = 512 KB)
    int* flags = (int*)d_ws;
    float4* G4 = (float4*)((char*)d_ws + 8192);

    hipMemsetAsync(d_ws, 0, 8192, stream);

    pcen_lookback<<<dim3(NBLK), dim3(256), 0, stream>>>(
        (const float4*)x, (const float4*)state,
        log_s, log_alpha, log_delta, log_r,
        (float4*)y, (float4*)new_state, G4, flags);
}

// Round 10
// 101.083 us; speedup vs baseline: 4.6104x; 1.1307x over previous
//
#include <hip/hip_runtime.h>
#include <math.h>

#define EPS 1e-6f

constexpr int B_ = 32;
constexpr int T_ = 8192;
constexpr int F_ = 128;
constexpr int FG = F_ / 4;   // 32 float4 feature-groups per row

// fast pow for strictly-positive base
__device__ __forceinline__ float fpow(float b, float e) {
    return exp2f(e * __log2f(b));
}

// -------- pass 1: per-chunk local sum with zero initial carry --------
// block = 256 threads = 8 chunk-slots x 32 feature-groups; each thread owns 4 features.
template<int NC>
__global__ __launch_bounds__(256, 8) void pcen_pass1(
    const float4* __restrict__ x4,
    const float*  __restrict__ log_s,
    float4* __restrict__ S4)
{
    constexpr int L = T_ / NC;
    const int fg    = threadIdx.x & 31;
    const int slot  = threadIdx.x >> 5;              // 0..7
    const int cb    = blockIdx.x % (NC / 8);
    const int b     = blockIdx.x / (NC / 8);
    const int chunk = cb * 8 + slot;

    const float4 lsv = reinterpret_cast<const float4*>(log_s)[fg];
    const float s0 = expf(lsv.x), s1 = expf(lsv.y), s2 = expf(lsv.z), s3 = expf(lsv.w);
    const float a0 = 1.f - s0,   a1 = 1.f - s1,    a2 = 1.f - s2,    a3 = 1.f - s3;

    const float4* xp = x4 + ((size_t)b * T_ + (size_t)chunk * L) * FG + fg;

    float c0 = 0.f, c1 = 0.f, c2 = 0.f, c3 = 0.f;
    #pragma unroll
    for (int i = 0; i < L; ++i) {
        const float4 xv = xp[(size_t)i * FG];
        c0 = fmaf(a0, c0, s0 * xv.x);
        c1 = fmaf(a1, c1, s1 * xv.y);
        c2 = fmaf(a2, c2, s2 * xv.z);
        c3 = fmaf(a3, c3, s3 * xv.w);
    }
    S4[((size_t)b * NC + chunk) * FG + fg] = make_float4(c0, c1, c2, c3);
}

// -------- pass 2: serial combine, IN-PLACE S -> carry-in --------
template<int NC>
__global__ __launch_bounds__(32) void pcen_pass2(
    const float4* __restrict__ state4,
    const float*  __restrict__ log_s,
    float4* __restrict__ S4,          // in: local sums; out: carry-in per chunk
    float4* __restrict__ new_state4)
{
    constexpr int L = T_ / NC;
    const int fg = threadIdx.x;   // 0..31
    const int b  = blockIdx.x;

    const float4 lsv = reinterpret_cast<const float4*>(log_s)[fg];
    const float aL0 = fpow(1.f - expf(lsv.x), (float)L);
    const float aL1 = fpow(1.f - expf(lsv.y), (float)L);
    const float aL2 = fpow(1.f - expf(lsv.z), (float)L);
    const float aL3 = fpow(1.f - expf(lsv.w), (float)L);

    float4 c = state4[(size_t)b * FG + fg];
    #pragma unroll 8
    for (int k = 0; k < NC; ++k) {
        const size_t idx = ((size_t)b * NC + k) * FG + fg;
        const float4 Sv = S4[idx];
        S4[idx] = c;                    // overwrite local sum with carry-in
        c.x = fmaf(aL0, c.x, Sv.x);
        c.y = fmaf(aL1, c.y, Sv.y);
        c.z = fmaf(aL2, c.z, Sv.z);
        c.w = fmaf(aL3, c.w, Sv.w);
    }
    new_state4[(size_t)b * FG + fg] = c;
}

// -------- pass 3: recurrence from exact carry + y --------
template<int NC>
__global__ __launch_bounds__(256, 8) void pcen_pass3(
    const float4* __restrict__ x4,
    const float*  __restrict__ log_s,
    const float*  __restrict__ log_alpha,
    const float*  __restrict__ log_delta,
    const float*  __restrict__ log_r,
    const float4* __restrict__ carry4,
    float4* __restrict__ y4)
{
    constexpr int L = T_ / NC;
    const int fg    = threadIdx.x & 31;
    const int slot  = threadIdx.x >> 5;
    const int cb    = blockIdx.x % (NC / 8);
    const int b     = blockIdx.x / (NC / 8);
    const int chunk = cb * 8 + slot;

    const float4 lsv = reinterpret_cast<const float4*>(log_s)[fg];
    const float s0 = expf(lsv.x), s1 = expf(lsv.y), s2 = expf(lsv.z), s3 = expf(lsv.w);
    const float a0 = 1.f - s0,   a1 = 1.f - s1,    a2 = 1.f - s2,    a3 = 1.f - s3;

    const float4 lav = reinterpret_cast<const float4*>(log_alpha)[fg];
    const float4 ldv = reinterpret_cast<const float4*>(log_delta)[fg];
    const float4 lrv = reinterpret_cast<const float4*>(log_r)[fg];
    const float na0 = -expf(lav.x), na1 = -expf(lav.y), na2 = -expf(lav.z), na3 = -expf(lav.w);
    const float d0 = expf(ldv.x), d1 = expf(ldv.y), d2 = expf(ldv.z), d3 = expf(ldv.w);
    const float r0 = expf(lrv.x), r1 = expf(lrv.y), r2 = expf(lrv.z), r3 = expf(lrv.w);
    const float dr0 = fpow(d0, r0), dr1 = fpow(d1, r1);
    const float dr2 = fpow(d2, r2), dr3 = fpow(d3, r3);

    float4 c = carry4[((size_t)b * NC + chunk) * FG + fg];

    const size_t base = ((size_t)b * T_ + (size_t)chunk * L) * FG + fg;
    const float4* xp = x4 + base;
    float4*       yp = y4 + base;

    #pragma unroll
    for (int i = 0; i < L; ++i) {
        const float4 xv = xp[(size_t)i * FG];

        c.x = fmaf(a0, c.x, s0 * xv.x);
        c.y = fmaf(a1, c.y, s1 * xv.y);
        c.z = fmaf(a2, c.z, s2 * xv.z);
        c.w = fmaf(a3, c.w, s3 * xv.w);

        // u = x * (EPS+E)^(-alpha);  y = (u + delta)^r - delta^r
        const float u0 = xv.x * exp2f(na0 * __log2f(EPS + c.x));
        const float u1 = xv.y * exp2f(na1 * __log2f(EPS + c.y));
        const float u2 = xv.z * exp2f(na2 * __log2f(EPS + c.z));
        const float u3 = xv.w * exp2f(na3 * __log2f(EPS + c.w));

        float4 yv;
        yv.x = exp2f(r0 * __log2f(u0 + d0)) - dr0;
        yv.y = exp2f(r1 * __log2f(u1 + d1)) - dr1;
        yv.z = exp2f(r2 * __log2f(u2 + d2)) - dr2;
        yv.w = exp2f(r3 * __log2f(u3 + d3)) - dr3;

        yp[(size_t)i * FG] = yv;
    }
}

template<int NC>
static void launch_all(const float* x, const float* state,
                       const float* log_s, const float* log_alpha,
                       const float* log_delta, const float* log_r,
                       float* y, float* new_state, float* ws, hipStream_t stream)
{
    const float4* x4      = (const float4*)x;
    const float4* state4  = (const float4*)state;
    float4* y4            = (float4*)y;
    float4* new_state4    = (float4*)new_state;
    float4* S4            = (float4*)ws;     // B*NC*FG float4 (dual-use S/carry)

    dim3 blk(256);
    dim3 grid(B_ * (NC / 8));

    pcen_pass1<NC><<<grid, blk, 0, stream>>>(x4, log_s, S4);
    pcen_pass2<NC><<<dim3(B_), dim3(32), 0, stream>>>(state4, log_s, S4, new_state4);
    pcen_pass3<NC><<<grid, blk, 0, stream>>>(x4, log_s, log_alpha, log_delta, log_r, S4, y4);
}

extern "C" void kernel_launch(void* const* d_in, const int* in_sizes, int n_in,
                              void* d_out, int out_size, void* d_ws, size_t ws_size,
                              hipStream_t stream)
{
    const float* x         = (const float*)d_in[0];
    const float* state     = (const float*)d_in[1];
    const float* log_s     = (const float*)d_in[2];
    const float* log_alpha = (const float*)d_in[3];
    const float* log_delta = (const float*)d_in[4];
    const float* log_r     = (const float*)d_in[5];

    float* y         = (float*)d_out;
    float* new_state = y + (size_t)B_ * T_ * F_;

    // workspace need: 1 buffer of B*NC*F floats (in-place S/carry)
    const size_t need512 = (size_t)B_ * 512 * F_ * sizeof(float);   // 8 MB
    const size_t need256 = (size_t)B_ * 256 * F_ * sizeof(float);   // 4 MB
    if (ws_size >= need512) {
        launch_all<512>(x, state, log_s, log_alpha, log_delta, log_r,
                        y, new_state, (float*)d_ws, stream);
    } else if (ws_size >= need256) {
        launch_all<256>(x, state, log_s, log_alpha, log_delta, log_r,
                        y, new_state, (float*)d_ws, stream);
    } else {
        launch_all<64>(x, state, log_s, log_alpha, log_delta, log_r,
                       y, new_state, (float*)d_ws, stream);
    }
}